// Round 1
// baseline (512.591 us; speedup 1.0000x reference)
//
#include <hip/hip_runtime.h>

#define NS 10000
#define DD 64
#define HH 128
#define EE 50000
#define SLOPE 0.01f

__device__ __forceinline__ float wave_sum64(float v) {
  #pragma unroll
  for (int m = 32; m >= 1; m >>= 1) v += __shfl_xor(v, m, 64);
  return v;
}

// h = leaky_relu(layer_norm(x)); one wave (64 lanes) per row, D==64.
__global__ __launch_bounds__(256) void k_ln(const float* __restrict__ x,
    const float* __restrict__ gamma, const float* __restrict__ beta,
    float* __restrict__ h) {
  int wid = threadIdx.x >> 6;
  int lane = threadIdx.x & 63;
  int row = blockIdx.x * 4 + wid;
  if (row >= NS) return;
  float v = x[row * DD + lane];
  float s = wave_sum64(v);
  float s2 = wave_sum64(v * v);
  float mu = s * (1.0f / 64.0f);
  float var = s2 * (1.0f / 64.0f) - mu * mu;
  float r = rsqrtf(var + 1e-5f);
  float hn = (v - mu) * r * gamma[lane] + beta[lane];
  h[row * DD + lane] = hn >= 0.f ? hn : SLOPE * hn;
}

// u = leaky_relu(ea @ w1 + b1)   [E,64]@[64,128]
__global__ __launch_bounds__(256) void k_u(const float* __restrict__ ea,
    const float* __restrict__ w1, const float* __restrict__ b1,
    float* __restrict__ u) {
  __shared__ float w1s[DD][HH];   // 32 KB
  __shared__ float eas[32][DD];   // 8 KB
  int t = threadIdx.x;
  #pragma unroll
  for (int i = 0; i < 32; ++i) {
    int idx = t + i * 256;
    w1s[idx >> 7][idx & 127] = w1[idx];
  }
  int row0 = blockIdx.x * 32;
  #pragma unroll
  for (int i = 0; i < 8; ++i) {
    int idx = t + i * 256;
    int r = idx >> 6, d = idx & 63;
    int gr = row0 + r;
    eas[r][d] = (gr < EE) ? ea[gr * DD + d] : 0.f;
  }
  __syncthreads();
  int r = t >> 3;
  int c0 = (t & 7) * 16;
  int gr = row0 + r;
  if (gr >= EE) return;
  float acc[16];
  #pragma unroll
  for (int j = 0; j < 16; ++j) acc[j] = b1[c0 + j];
  for (int d = 0; d < DD; ++d) {
    float a = eas[r][d];
    #pragma unroll
    for (int j = 0; j < 16; ++j) acc[j] += a * w1s[d][c0 + j];
  }
  #pragma unroll
  for (int j = 0; j < 16; ++j) {
    float vv = acc[j];
    u[(size_t)gr * HH + c0 + j] = vv >= 0.f ? vv : SLOPE * vv;
  }
}

// C[n,64] = A[n,64] @ B[64,64]  (B row-major [d][f])
__global__ __launch_bounds__(256) void k_gemm64(const float* __restrict__ A,
    const float* __restrict__ B, float* __restrict__ C, int n) {
  __shared__ float Bs[DD][DD + 1];
  __shared__ float As[32][DD];
  int t = threadIdx.x;
  #pragma unroll
  for (int i = 0; i < 16; ++i) {
    int idx = t + i * 256;
    Bs[idx >> 6][idx & 63] = B[idx];
  }
  int row0 = blockIdx.x * 32;
  #pragma unroll
  for (int i = 0; i < 8; ++i) {
    int idx = t + i * 256;
    int r = idx >> 6, d = idx & 63;
    int gr = row0 + r;
    As[r][d] = (gr < n) ? A[gr * DD + d] : 0.f;
  }
  __syncthreads();
  int r = t >> 3;
  int c0 = (t & 7) * 8;
  int gr = row0 + r;
  if (gr >= n) return;
  float acc[8] = {};
  for (int d = 0; d < DD; ++d) {
    float a = As[r][d];
    #pragma unroll
    for (int j = 0; j < 8; ++j) acc[j] += a * Bs[d][c0 + j];
  }
  #pragma unroll
  for (int j = 0; j < 8; ++j) C[(size_t)gr * DD + c0 + j] = acc[j];
}

// T[n, gcol] = sum_d h[n,d] * w2[k*4096 + d*64 + f0 + fc],
// gcol in [0, 128*Fc), k = gcol>>lFc, fc = gcol & (Fc-1).
__global__ __launch_bounds__(256) void k_T(const float* __restrict__ h,
    const float* __restrict__ w2, float* __restrict__ T, int f0, int lFc) {
  __shared__ float hs[64][65];    // ~16.6 KB
  __shared__ float Bs[64][128];   // 32 KB
  int t = threadIdx.x;
  int row0 = blockIdx.x * 64;
  int col0 = blockIdx.y * 128;
  int Fcm = (1 << lFc) - 1;
  #pragma unroll
  for (int i = 0; i < 16; ++i) {
    int idx = t + i * 256;
    int r = idx >> 6, d = idx & 63;
    int gr = row0 + r;
    hs[r][d] = (gr < NS) ? h[gr * DD + d] : 0.f;
  }
  #pragma unroll
  for (int i = 0; i < 32; ++i) {
    int idx = t + i * 256;
    int d = idx >> 7, cc = idx & 127;
    int gcol = col0 + cc;
    int k = gcol >> lFc;
    int fc = gcol & Fcm;
    Bs[d][cc] = w2[k * (DD * DD) + d * DD + f0 + fc];
  }
  __syncthreads();
  int ty = t >> 4;   // 4 rows each
  int tx = t & 15;   // 8 cols each
  float acc[4][8] = {};
  for (int d = 0; d < DD; ++d) {
    float b[8];
    #pragma unroll
    for (int j = 0; j < 8; ++j) b[j] = Bs[d][tx * 8 + j];
    #pragma unroll
    for (int i = 0; i < 4; ++i) {
      float a = hs[ty * 4 + i][d];
      #pragma unroll
      for (int j = 0; j < 8; ++j) acc[i][j] += a * b[j];
    }
  }
  int ldT = HH << lFc;
  #pragma unroll
  for (int i = 0; i < 4; ++i) {
    int gr = row0 + ty * 4 + i;
    if (gr < NS) {
      float* dst = &T[(size_t)gr * ldT + col0 + tx * 8];
      #pragma unroll
      for (int j = 0; j < 8; ++j) dst[j] = acc[i][j];
    }
  }
}

__global__ __launch_bounds__(256) void k_cnt(const int* __restrict__ ei,
                                             int* __restrict__ cnt) {
  int e = blockIdx.x * 256 + threadIdx.x;
  if (e < EE) atomicAdd(&cnt[ei[EE + e]], 1);
}

// msg[e, f0+fc] = sum_k u[e,k] * T[src, k*Fc+fc] + c[src, f0+fc]; atomic into agg[dst].
__global__ __launch_bounds__(256) void k_msg(const float* __restrict__ u,
    const float* __restrict__ T, const float* __restrict__ c,
    const int* __restrict__ ei, float* __restrict__ agg, int f0, int lFc) {
  int Fc = 1 << lFc;
  int t = threadIdx.x;
  int eLocal = t >> lFc;
  int fc = t & (Fc - 1);
  int EB = 256 >> lFc;
  int e = blockIdx.x * EB + eLocal;
  if (e >= EE) return;
  int s = ei[e];
  int dd = ei[EE + e];
  int ldT = HH << lFc;
  const float* Trow = &T[(size_t)s * ldT + fc];
  const float* urow = &u[(size_t)e * HH];
  float acc = 0.f;
  #pragma unroll 4
  for (int k = 0; k < HH; ++k) {
    acc += urow[k] * Trow[(size_t)k << lFc];
  }
  acc += c[(size_t)s * DD + f0 + fc];
  atomicAdd(&agg[(size_t)dd * DD + f0 + fc], acc);
}

// out = x + agg/max(cnt,1) + h@root + bias
__global__ __launch_bounds__(256) void k_final(const float* __restrict__ x,
    const float* __restrict__ h, const float* __restrict__ root,
    const float* __restrict__ bias, const float* __restrict__ agg,
    const int* __restrict__ cnt, float* __restrict__ out) {
  __shared__ float Bs[DD][DD + 1];
  __shared__ float As[32][DD];
  int t = threadIdx.x;
  #pragma unroll
  for (int i = 0; i < 16; ++i) {
    int idx = t + i * 256;
    Bs[idx >> 6][idx & 63] = root[idx];
  }
  int row0 = blockIdx.x * 32;
  #pragma unroll
  for (int i = 0; i < 8; ++i) {
    int idx = t + i * 256;
    int r = idx >> 6, d = idx & 63;
    int gr = row0 + r;
    As[r][d] = (gr < NS) ? h[gr * DD + d] : 0.f;
  }
  __syncthreads();
  int r = t >> 3;
  int c0 = (t & 7) * 8;
  int gr = row0 + r;
  if (gr >= NS) return;
  float acc[8] = {};
  for (int d = 0; d < DD; ++d) {
    float a = As[r][d];
    #pragma unroll
    for (int j = 0; j < 8; ++j) acc[j] += a * Bs[d][c0 + j];
  }
  float inv = 1.0f / fmaxf((float)cnt[gr], 1.0f);
  #pragma unroll
  for (int j = 0; j < 8; ++j) {
    size_t gi = (size_t)gr * DD + c0 + j;
    out[gi] = x[gi] + agg[gi] * inv + acc[j] + bias[c0 + j];
  }
}

extern "C" void kernel_launch(void* const* d_in, const int* in_sizes, int n_in,
                              void* d_out, int out_size, void* d_ws, size_t ws_size,
                              hipStream_t stream) {
  const float* x     = (const float*)d_in[0];
  const float* ea    = (const float*)d_in[1];
  const float* gamma = (const float*)d_in[2];
  const float* beta  = (const float*)d_in[3];
  const float* w1    = (const float*)d_in[4];
  const float* b1    = (const float*)d_in[5];
  const float* w2    = (const float*)d_in[6];
  const float* b2    = (const float*)d_in[7];
  const float* root  = (const float*)d_in[8];
  const float* bias  = (const float*)d_in[9];
  const int*   ei    = (const int*)d_in[10];
  float* out = (float*)d_out;

  char* p = (char*)d_ws;
  auto carve = [&](size_t bytes) {
    char* q = p;
    p += (bytes + 255) & ~(size_t)255;
    return q;
  };
  float* h   = (float*)carve(sizeof(float) * NS * DD);
  float* cc  = (float*)carve(sizeof(float) * NS * DD);
  float* agg = (float*)carve(sizeof(float) * NS * DD);
  int*   cnt = (int*)carve(sizeof(int) * NS);
  float* u   = (float*)carve(sizeof(float) * (size_t)EE * HH);
  size_t fixed = (size_t)(p - (char*)d_ws);

  // Pick largest Fc in {16,8,4,2,1} whose T-chunk fits the workspace.
  int lFc = 4;
  while (lFc > 0 &&
         fixed + sizeof(float) * (size_t)NS * HH * ((size_t)1 << lFc) > ws_size)
    --lFc;
  float* T = (float*)carve(sizeof(float) * (size_t)NS * HH * ((size_t)1 << lFc));
  int Fc = 1 << lFc;

  hipMemsetAsync(agg, 0, sizeof(float) * NS * DD, stream);
  hipMemsetAsync(cnt, 0, sizeof(int) * NS, stream);

  k_ln<<<dim3((NS + 3) / 4), dim3(256), 0, stream>>>(x, gamma, beta, h);
  k_u<<<dim3((EE + 31) / 32), dim3(256), 0, stream>>>(ea, w1, b1, u);
  k_gemm64<<<dim3((NS + 31) / 32), dim3(256), 0, stream>>>(h, b2, cc, NS);
  k_cnt<<<dim3((EE + 255) / 256), dim3(256), 0, stream>>>(ei, cnt);

  int nChunks = DD / Fc;
  for (int ch = 0; ch < nChunks; ++ch) {
    int f0 = ch * Fc;
    k_T<<<dim3((NS + 63) / 64, Fc), dim3(256), 0, stream>>>(h, w2, T, f0, lFc);
    k_msg<<<dim3((EE * Fc + 255) / 256), dim3(256), 0, stream>>>(u, T, cc, ei,
                                                                 agg, f0, lFc);
  }
  k_final<<<dim3((NS + 31) / 32), dim3(256), 0, stream>>>(x, h, root, bias, agg,
                                                          cnt, out);
}

// Round 2
// 223.605 us; speedup vs baseline: 2.2924x; 2.2924x over previous
//
#include <hip/hip_runtime.h>

#define NS 10000
#define DD 64
#define HH 128
#define EE 50000
#define SLOPE 0.01f

typedef __attribute__((ext_vector_type(8))) short short8;
typedef __attribute__((ext_vector_type(4))) float f32x4;

static __device__ __forceinline__ unsigned short f2bf(float f) {
  unsigned int u = __float_as_uint(f);
  u += 0x7fff + ((u >> 16) & 1);   // round-to-nearest-even
  return (unsigned short)(u >> 16);
}
static __device__ __forceinline__ float bf2f(unsigned short s) {
  return __uint_as_float((unsigned int)s << 16);
}
static __device__ __forceinline__ float rdlane(float v, int k) {
  return __uint_as_float(__builtin_amdgcn_readlane(__float_as_uint(v), k));
}

__device__ __forceinline__ float wave_sum64(float v) {
  #pragma unroll
  for (int m = 32; m >= 1; m >>= 1) v += __shfl_xor(v, m, 64);
  return v;
}

// h = leaky_relu(layer_norm(x)); also emit bf16 copy for MFMA.
__global__ __launch_bounds__(256) void k_ln(const float* __restrict__ x,
    const float* __restrict__ gamma, const float* __restrict__ beta,
    float* __restrict__ h, unsigned short* __restrict__ hbf) {
  int wid = threadIdx.x >> 6;
  int lane = threadIdx.x & 63;
  int row = blockIdx.x * 4 + wid;
  if (row >= NS) return;
  float v = x[row * DD + lane];
  float s = wave_sum64(v);
  float s2 = wave_sum64(v * v);
  float mu = s * (1.0f / 64.0f);
  float var = s2 * (1.0f / 64.0f) - mu * mu;
  float r = rsqrtf(var + 1e-5f);
  float hn = (v - mu) * r * gamma[lane] + beta[lane];
  float hv = hn >= 0.f ? hn : SLOPE * hn;
  h[row * DD + lane] = hv;
  hbf[row * DD + lane] = f2bf(hv);
}

// w2t[(k*64+f)*64 + d] = bf16(w2[k*4096 + d*64 + f])  -- B^T for k_T_mfma.
__global__ __launch_bounds__(256) void k_cast_w2t(const float* __restrict__ w2,
    unsigned short* __restrict__ w2t) {
  int tid = blockIdx.x * 256 + threadIdx.x;   // 524288 total
  int c = tid >> 6;          // k*64+f
  int d = tid & 63;
  int k = c >> 6, f = c & 63;
  w2t[tid] = f2bf(w2[k * (DD * DD) + d * DD + f]);
}

// u = leaky_relu(ea @ w1 + b1)   [E,64]@[64,128]
__global__ __launch_bounds__(256) void k_u(const float* __restrict__ ea,
    const float* __restrict__ w1, const float* __restrict__ b1,
    float* __restrict__ u) {
  __shared__ float w1s[DD][HH];
  __shared__ float eas[32][DD];
  int t = threadIdx.x;
  #pragma unroll
  for (int i = 0; i < 32; ++i) {
    int idx = t + i * 256;
    w1s[idx >> 7][idx & 127] = w1[idx];
  }
  int row0 = blockIdx.x * 32;
  #pragma unroll
  for (int i = 0; i < 8; ++i) {
    int idx = t + i * 256;
    int r = idx >> 6, d = idx & 63;
    int gr = row0 + r;
    eas[r][d] = (gr < EE) ? ea[gr * DD + d] : 0.f;
  }
  __syncthreads();
  int r = t >> 3;
  int c0 = (t & 7) * 16;
  int gr = row0 + r;
  if (gr >= EE) return;
  float acc[16];
  #pragma unroll
  for (int j = 0; j < 16; ++j) acc[j] = b1[c0 + j];
  for (int d = 0; d < DD; ++d) {
    float a = eas[r][d];
    #pragma unroll
    for (int j = 0; j < 16; ++j) acc[j] += a * w1s[d][c0 + j];
  }
  #pragma unroll
  for (int j = 0; j < 16; ++j) {
    float vv = acc[j];
    u[(size_t)gr * HH + c0 + j] = vv >= 0.f ? vv : SLOPE * vv;
  }
}

// C[n,64] = A[n,64] @ B[64,64]
__global__ __launch_bounds__(256) void k_gemm64(const float* __restrict__ A,
    const float* __restrict__ B, float* __restrict__ C, int n) {
  __shared__ float Bs[DD][DD + 1];
  __shared__ float As[32][DD];
  int t = threadIdx.x;
  #pragma unroll
  for (int i = 0; i < 16; ++i) {
    int idx = t + i * 256;
    Bs[idx >> 6][idx & 63] = B[idx];
  }
  int row0 = blockIdx.x * 32;
  #pragma unroll
  for (int i = 0; i < 8; ++i) {
    int idx = t + i * 256;
    int r = idx >> 6, d = idx & 63;
    int gr = row0 + r;
    As[r][d] = (gr < n) ? A[gr * DD + d] : 0.f;
  }
  __syncthreads();
  int r = t >> 3;
  int c0 = (t & 7) * 8;
  int gr = row0 + r;
  if (gr >= n) return;
  float acc[8] = {};
  for (int d = 0; d < DD; ++d) {
    float a = As[r][d];
    #pragma unroll
    for (int j = 0; j < 8; ++j) acc[j] += a * Bs[d][c0 + j];
  }
  #pragma unroll
  for (int j = 0; j < 8; ++j) C[(size_t)gr * DD + c0 + j] = acc[j];
}

__global__ __launch_bounds__(256) void k_cnt2(const int* __restrict__ ei,
    int* __restrict__ cntsrc, int* __restrict__ cntdst) {
  int e = blockIdx.x * 256 + threadIdx.x;
  if (e < EE) {
    atomicAdd(&cntsrc[ei[e]], 1);
    atomicAdd(&cntdst[ei[EE + e]], 1);
  }
}

// single-block exclusive scan of cntsrc -> rowptr[N+1], also init cursor.
__global__ __launch_bounds__(256) void k_scan(const int* __restrict__ cntsrc,
    int* __restrict__ rowptr, int* __restrict__ cursor) {
  __shared__ int ps[256];
  int t = threadIdx.x;
  const int CH = (NS + 255) / 256;
  int base = t * CH;
  int sum = 0;
  for (int i = 0; i < CH; ++i) {
    int idx = base + i;
    if (idx < NS) sum += cntsrc[idx];
  }
  ps[t] = sum;
  __syncthreads();
  for (int off = 1; off < 256; off <<= 1) {
    int v = (t >= off) ? ps[t - off] : 0;
    __syncthreads();
    ps[t] += v;
    __syncthreads();
  }
  int run = ps[t] - sum;
  for (int i = 0; i < CH; ++i) {
    int idx = base + i;
    if (idx < NS) {
      rowptr[idx] = run;
      cursor[idx] = run;
      run += cntsrc[idx];
    }
  }
  if (t == 255) rowptr[NS] = run;
}

__global__ __launch_bounds__(256) void k_scatter(const int* __restrict__ ei,
    int* __restrict__ cursor, int* __restrict__ eord) {
  int e = blockIdx.x * 256 + threadIdx.x;
  if (e < EE) {
    int s = ei[e];
    int pos = atomicAdd(&cursor[s], 1);
    eord[pos] = e;
  }
}

// T (bf16) = hbf @ w2t^T : A[NS,64] x B[64, HH<<lFc] tile 64x256, 4 waves.
__global__ __launch_bounds__(256) void k_T_mfma(
    const unsigned short* __restrict__ hbf, const unsigned short* __restrict__ w2t,
    unsigned short* __restrict__ T, int f0, int lFc) {
  __shared__ unsigned short As[64][72];
  __shared__ unsigned short Bs[256][72];
  int t = threadIdx.x;
  int row0 = blockIdx.x * 64;
  int col0 = blockIdx.y * 256;
  int Fcm = (1 << lFc) - 1;
  #pragma unroll
  for (int i = 0; i < 2; ++i) {
    int idx = t + i * 256;            // 0..511
    int r = idx >> 3, cc = (idx & 7) * 8;
    int gr = row0 + r;
    short8 v = {};
    if (gr < NS) v = *(const short8*)(hbf + (size_t)gr * DD + cc);
    *(short8*)(&As[r][cc]) = v;
  }
  #pragma unroll
  for (int i = 0; i < 8; ++i) {
    int idx = t + i * 256;            // 0..2047
    int cL = idx >> 3, rr = (idx & 7) * 8;
    int gc = col0 + cL;
    int k = gc >> lFc, f = f0 + (gc & Fcm);
    int c = k * DD + f;               // col in w2t [8192][64]
    short8 v = *(const short8*)(w2t + (size_t)c * DD + rr);
    *(short8*)(&Bs[cL][rr]) = v;
  }
  __syncthreads();
  int w = t >> 6, lane = t & 63;
  int lr = lane & 15, lg = lane >> 4;
  f32x4 acc[4][4] = {};
  #pragma unroll
  for (int kk = 0; kk < 64; kk += 32) {
    short8 a[4], b[4];
    #pragma unroll
    for (int mi = 0; mi < 4; ++mi)
      a[mi] = *(const short8*)(&As[mi * 16 + lr][kk + lg * 8]);
    #pragma unroll
    for (int ni = 0; ni < 4; ++ni)
      b[ni] = *(const short8*)(&Bs[w * 64 + ni * 16 + lr][kk + lg * 8]);
    #pragma unroll
    for (int mi = 0; mi < 4; ++mi)
      #pragma unroll
      for (int ni = 0; ni < 4; ++ni)
        acc[mi][ni] = __builtin_amdgcn_mfma_f32_16x16x32_bf16(
            a[mi], b[ni], acc[mi][ni], 0, 0, 0);
  }
  size_t ldT = (size_t)(HH << lFc);
  #pragma unroll
  for (int mi = 0; mi < 4; ++mi) {
    int gr0 = row0 + mi * 16 + lg * 4;
    #pragma unroll
    for (int ni = 0; ni < 4; ++ni) {
      int gc = col0 + w * 64 + ni * 16 + lr;
      #pragma unroll
      for (int reg = 0; reg < 4; ++reg) {
        int gr = gr0 + reg;
        if (gr < NS) T[(size_t)gr * ldT + gc] = f2bf(acc[mi][ni][reg]);
      }
    }
  }
}

// CSR-by-src message pass, full-f (lFc==6): block = src node, T row in LDS.
__global__ __launch_bounds__(256) void k_msg_csr(const float* __restrict__ u,
    const unsigned short* __restrict__ T, const float* __restrict__ c,
    const int* __restrict__ ei, const int* __restrict__ rowptr,
    const int* __restrict__ eord, float* __restrict__ agg) {
  int s = blockIdx.x;
  int beg = rowptr[s], end = rowptr[s + 1];
  if (beg == end) return;
  __shared__ float Ts[HH][DD];
  __shared__ float cs[DD];
  int t = threadIdx.x;
  const unsigned short* Tr = T + (size_t)s * (HH * DD);
  #pragma unroll
  for (int i = 0; i < 4; ++i) {
    int idx = (t + i * 256) * 8;
    short8 v = *(const short8*)(Tr + idx);
    float* dst = &Ts[idx >> 6][idx & 63];
    #pragma unroll
    for (int j = 0; j < 8; ++j) dst[j] = bf2f((unsigned short)v[j]);
  }
  if (t < DD) cs[t] = c[s * DD + t];
  __syncthreads();
  int wid = t >> 6, lane = t & 63;
  float csl = cs[lane];
  for (int j = beg + wid * 2; j < end; j += 8) {
    int e0 = eord[j];
    bool has1 = (j + 1) < end;
    int e1 = has1 ? eord[j + 1] : e0;
    int d0 = ei[EE + e0], d1 = ei[EE + e1];
    const float* u0p = u + (size_t)e0 * HH;
    const float* u1p = u + (size_t)e1 * HH;
    float u00 = u0p[lane], u01 = u0p[64 + lane];
    float u10 = u1p[lane], u11 = u1p[64 + lane];
    float a0 = csl, a0b = 0.f, a1 = csl, a1b = 0.f;
    #pragma unroll
    for (int k = 0; k < 64; k += 2) {
      float t0 = Ts[k][lane], t1 = Ts[k + 1][lane];
      a0  += rdlane(u00, k) * t0;
      a0b += rdlane(u00, k + 1) * t1;
      a1  += rdlane(u10, k) * t0;
      a1b += rdlane(u10, k + 1) * t1;
    }
    #pragma unroll
    for (int k = 0; k < 64; k += 2) {
      float t0 = Ts[64 + k][lane], t1 = Ts[64 + k + 1][lane];
      a0  += rdlane(u01, k) * t0;
      a0b += rdlane(u01, k + 1) * t1;
      a1  += rdlane(u11, k) * t0;
      a1b += rdlane(u11, k + 1) * t1;
    }
    atomicAdd(&agg[(size_t)d0 * DD + lane], a0 + a0b);
    if (has1) atomicAdd(&agg[(size_t)d1 * DD + lane], a1 + a1b);
  }
}

// fallback: chunked gather (bf16 T), any lFc.
__global__ __launch_bounds__(256) void k_msg_g(const float* __restrict__ u,
    const unsigned short* __restrict__ T, const float* __restrict__ c,
    const int* __restrict__ ei, float* __restrict__ agg, int f0, int lFc) {
  int Fc = 1 << lFc;
  int t = threadIdx.x;
  int eLocal = t >> lFc;
  int fc = t & (Fc - 1);
  int EB = 256 >> lFc;
  int e = blockIdx.x * EB + eLocal;
  if (e >= EE) return;
  int s = ei[e];
  int dd = ei[EE + e];
  int ldT = HH << lFc;
  const unsigned short* Trow = T + (size_t)s * ldT + fc;
  const float* urow = u + (size_t)e * HH;
  float acc = 0.f;
  #pragma unroll 4
  for (int k = 0; k < HH; ++k)
    acc += urow[k] * bf2f(Trow[(size_t)k << lFc]);
  acc += c[(size_t)s * DD + f0 + fc];
  atomicAdd(&agg[(size_t)dd * DD + f0 + fc], acc);
}

// out = x + agg/max(cnt,1) + h@root + bias
__global__ __launch_bounds__(256) void k_final(const float* __restrict__ x,
    const float* __restrict__ h, const float* __restrict__ root,
    const float* __restrict__ bias, const float* __restrict__ agg,
    const int* __restrict__ cnt, float* __restrict__ out) {
  __shared__ float Bs[DD][DD + 1];
  __shared__ float As[32][DD];
  int t = threadIdx.x;
  #pragma unroll
  for (int i = 0; i < 16; ++i) {
    int idx = t + i * 256;
    Bs[idx >> 6][idx & 63] = root[idx];
  }
  int row0 = blockIdx.x * 32;
  #pragma unroll
  for (int i = 0; i < 8; ++i) {
    int idx = t + i * 256;
    int r = idx >> 6, d = idx & 63;
    int gr = row0 + r;
    As[r][d] = (gr < NS) ? h[gr * DD + d] : 0.f;
  }
  __syncthreads();
  int r = t >> 3;
  int c0 = (t & 7) * 8;
  int gr = row0 + r;
  if (gr >= NS) return;
  float acc[8] = {};
  for (int d = 0; d < DD; ++d) {
    float a = As[r][d];
    #pragma unroll
    for (int j = 0; j < 8; ++j) acc[j] += a * Bs[d][c0 + j];
  }
  float inv = 1.0f / fmaxf((float)cnt[gr], 1.0f);
  #pragma unroll
  for (int j = 0; j < 8; ++j) {
    size_t gi = (size_t)gr * DD + c0 + j;
    out[gi] = x[gi] + agg[gi] * inv + acc[j] + bias[c0 + j];
  }
}

extern "C" void kernel_launch(void* const* d_in, const int* in_sizes, int n_in,
                              void* d_out, int out_size, void* d_ws, size_t ws_size,
                              hipStream_t stream) {
  const float* x     = (const float*)d_in[0];
  const float* ea    = (const float*)d_in[1];
  const float* gamma = (const float*)d_in[2];
  const float* beta  = (const float*)d_in[3];
  const float* w1    = (const float*)d_in[4];
  const float* b1    = (const float*)d_in[5];
  const float* w2    = (const float*)d_in[6];
  const float* b2    = (const float*)d_in[7];
  const float* root  = (const float*)d_in[8];
  const float* bias  = (const float*)d_in[9];
  const int*   ei    = (const int*)d_in[10];
  float* out = (float*)d_out;

  char* p = (char*)d_ws;
  auto carve = [&](size_t bytes) {
    char* q = p;
    p += (bytes + 255) & ~(size_t)255;
    return q;
  };
  float* h            = (float*)carve(sizeof(float) * NS * DD);
  unsigned short* hbf = (unsigned short*)carve(sizeof(short) * NS * DD);
  float* cc           = (float*)carve(sizeof(float) * NS * DD);
  float* agg          = (float*)carve(sizeof(float) * NS * DD);
  int* cntdst         = (int*)carve(sizeof(int) * NS);
  int* cntsrc         = (int*)carve(sizeof(int) * NS);
  int* rowptr         = (int*)carve(sizeof(int) * (NS + 1));
  int* cursor         = (int*)carve(sizeof(int) * NS);
  int* eord           = (int*)carve(sizeof(int) * EE);
  unsigned short* w2t = (unsigned short*)carve(sizeof(short) * HH * DD * DD);
  float* u            = (float*)carve(sizeof(float) * (size_t)EE * HH);
  size_t fixed = (size_t)(p - (char*)d_ws);

  int lFc = 6;   // full-f if it fits (bf16 T = 164 MB)
  while (lFc > 1 &&
         fixed + sizeof(short) * (size_t)NS * (HH << lFc) > ws_size)
    --lFc;
  unsigned short* T = (unsigned short*)carve(sizeof(short) * (size_t)NS * (HH << lFc));

  hipMemsetAsync(agg, 0, sizeof(float) * NS * DD, stream);
  hipMemsetAsync(cntdst, 0, sizeof(int) * NS, stream);
  hipMemsetAsync(cntsrc, 0, sizeof(int) * NS, stream);

  k_ln<<<dim3((NS + 3) / 4), dim3(256), 0, stream>>>(x, gamma, beta, h, hbf);
  k_cast_w2t<<<dim3(HH * DD * DD / 256), dim3(256), 0, stream>>>(w2, w2t);
  k_u<<<dim3((EE + 31) / 32), dim3(256), 0, stream>>>(ea, w1, b1, u);
  k_gemm64<<<dim3((NS + 31) / 32), dim3(256), 0, stream>>>(h, b2, cc, NS);
  k_cnt2<<<dim3((EE + 255) / 256), dim3(256), 0, stream>>>(ei, cntsrc, cntdst);
  k_scan<<<dim3(1), dim3(256), 0, stream>>>(cntsrc, rowptr, cursor);
  k_scatter<<<dim3((EE + 255) / 256), dim3(256), 0, stream>>>(ei, cursor, eord);

  if (lFc == 6) {
    k_T_mfma<<<dim3((NS + 63) / 64, (HH << 6) / 256), dim3(256), 0, stream>>>(
        hbf, w2t, T, 0, 6);
    k_msg_csr<<<dim3(NS), dim3(256), 0, stream>>>(u, T, cc, ei, rowptr, eord, agg);
  } else {
    int Fc = 1 << lFc;
    int nChunks = DD / Fc;
    for (int ch = 0; ch < nChunks; ++ch) {
      int f0 = ch * Fc;
      k_T_mfma<<<dim3((NS + 63) / 64, (HH << lFc) / 256), dim3(256), 0, stream>>>(
          hbf, w2t, T, f0, lFc);
      k_msg_g<<<dim3((EE * Fc + 255) / 256), dim3(256), 0, stream>>>(
          u, T, cc, ei, agg, f0, lFc);
    }
  }
  k_final<<<dim3((NS + 31) / 32), dim3(256), 0, stream>>>(x, h, root, bias, agg,
                                                          cntdst, out);
}